// Round 13
// baseline (110.697 us; speedup 1.0000x reference)
//
#include <hip/hip_runtime.h>

// Problem constants (fixed by the reference)
#define NB    8
#define NPTS  4096
#define KNN   16
#define CG    16          // coarse cells per axis; cell = 0.0625
#define NCC   (CG * CG)   // 256 cells per batch
#define PCAP  24          // passer cap per query (avg ~1.4; never hit)

// r^2 exactly as the reference: RADIUS = 5.0/480 in f64, squared in f64,
// rounded to f32 by weak promotion in `d2 < radius*radius`.
#define R2F ((float)((5.0 / 480.0) * (5.0 / 480.0)))
// Window half-width for cell pruning: max true pass distance
// sqrt(R2F + 5e-7) ~= 0.010441; 0.011 leaves ample margin. 2*WIN < cell.
#define WIN 0.011f

// ---------------------------------------------------------------------------
// R13 = MEASUREMENT ROUND. Kernel source is byte-identical to R12 (verified
// 86.65us, absmax 0.0). The ONLY change: kernel_launch enqueues k_all TWICE.
// k_all is idempotent (reads only inputs, no workspace, unconditionally
// writes every out element with deterministic values -> second run writes
// identical bytes), so correctness is unchanged and
//     P(k_all) = dur(R13) - dur(R12)
// measures the payload kernel directly -- the number three rounds of
// modeling couldn't pin down (bottom-up says ~6-12us; subtraction vs R8's
// anchors says ~31us; every bottom-up-guided edit was neutral).
// Pre-committed read: ~117 -> P~31, attack kernel structure next;
// ~96-100 -> P~10-14, payload near floor, gap is ~30-35us fixed; between
// -> scale expectations accordingly.
// ---------------------------------------------------------------------------
__global__ __launch_bounds__(1024, 8) void k_all(
    const float4* __restrict__ xytp4, const float* __restrict__ W1,
    const float* __restrict__ b1, const float* __restrict__ W2,
    const float* __restrict__ b2, float* __restrict__ out) {
#pragma clang fp contract(off)
  // Region A (32KB): csrX[4096] + csrY[4096]  ->  hsT[128][64] after ph3.
  __shared__ __align__(16) char smemA[32768];
  __shared__ unsigned short csrIdx[4096];     // point index per CSR slot
  __shared__ int offs[NCC + 1];               // CSR starts (exclusive scan)
  __shared__ int cellcnt[NCC];                // counts, then scatter cursor
  __shared__ unsigned int plist[64 * PCAP];   // packed (idx<<12)|pos
  __shared__ int pcnt[64];
  __shared__ unsigned short idxposT[KNN][64]; // [slot][query] -> CSR pos
  __shared__ float embT[32][64];              // [k][query]

  float* csrX = (float*)smemA;                      // [4096]
  float* csrY = (float*)(smemA + 16384);            // [4096]
  float(*hsT)[64] = (float(*)[64])smemA;            // 128 x 64 (after ph3)

  const int t = threadIdx.x;
  const int p = t & 63;                       // lane
  const int q = t >> 6;                       // wave id 0..15, uniform
  const int pbase = blockIdx.x * 64;          // global query base
  const int bb = pbase & ~4095;               // batch point base (global)
  const int lqbase = pbase & 4095;            // batch-local query base

  // ---- build 1: load batch points into registers, count cells ----
  float4 Preg[4];
  int cellreg[4];
#pragma unroll
  for (int r = 0; r < 4; ++r) Preg[r] = xytp4[bb + t + 1024 * r];
  if (t < NCC) cellcnt[t] = 0;
  __syncthreads();
#pragma unroll
  for (int r = 0; r < 4; ++r) {
    int cx = min(CG - 1, max(0, (int)(Preg[r].y * (float)CG)));
    int cy = min(CG - 1, max(0, (int)(Preg[r].z * (float)CG)));
    cellreg[r] = cy * CG + cx;
    atomicAdd(&cellcnt[cellreg[r]], 1);
  }
  __syncthreads();

  // ---- build 2: wave 0 exclusive-scans 256 counts (4 cells/lane) ----
  if (q == 0) {
    int b4 = p * 4;
    int s0 = cellcnt[b4], s1 = cellcnt[b4 + 1], s2 = cellcnt[b4 + 2],
        s3 = cellcnt[b4 + 3];
    int tot = s0 + s1 + s2 + s3;
    int inc = tot;
#pragma unroll
    for (int d = 1; d < 64; d <<= 1) {
      int up = __shfl_up(inc, d);
      if (p >= d) inc += up;
    }
    int ex = inc - tot;
    offs[b4] = ex; offs[b4 + 1] = ex + s0;
    offs[b4 + 2] = ex + s0 + s1; offs[b4 + 3] = ex + s0 + s1 + s2;
    if (p == 63) offs[NCC] = inc;
    cellcnt[b4] = ex; cellcnt[b4 + 1] = ex + s0;        // -> cursors
    cellcnt[b4 + 2] = ex + s0 + s1; cellcnt[b4 + 3] = ex + s0 + s1 + s2;
  }
  __syncthreads();

  // ---- build 3: scatter (x, y, idx) into CSR (order scrambled) ----
#pragma unroll
  for (int r = 0; r < 4; ++r) {
    int pos = atomicAdd(&cellcnt[cellreg[r]], 1);
    csrX[pos] = Preg[r].y; csrY[pos] = Preg[r].z;
    csrIdx[pos] = (unsigned short)(t + 1024 * r);
  }
  __syncthreads();

  // ---- scan: wave q, queries 4q..4q+3; <=2x2 cell window each ----
  {
    const int q0 = q * 4;
    const unsigned long long below = (1ull << p) - 1;
#pragma unroll
    for (int g = 0; g < 4; ++g) {
      int lq = q0 + g;
      float4 P = xytp4[pbase + lq];           // uniform addr -> broadcast
      float xn = P.y, yn = P.z;
      float sqn = xn * xn + yn * yn;          // ref sq chain
      int cxlo = max(0, (int)((xn - WIN) * (float)CG));
      int cxhi = min(CG - 1, (int)((xn + WIN) * (float)CG));
      int cylo = max(0, (int)((yn - WIN) * (float)CG));
      int cyhi = min(CG - 1, (int)((yn + WIN) * (float)CG));
      int cnt = 0;
      for (int cy_ = cylo; cy_ <= cyhi; ++cy_)
        for (int cx_ = cxlo; cx_ <= cxhi; ++cx_) {
          int cell = cy_ * CG + cx_;
          int st = offs[cell], en = offs[cell + 1];
          for (int base = st; base < en; base += 64) {
            int e = base + p;
            bool act = e < en;
            int ee = act ? e : st;            // clamp to a valid address
            float cx2 = csrX[ee], cy2 = csrY[ee];
            float cs2 = cx2 * cx2 + cy2 * cy2;    // == dropped csrSQ bits
            float tt = fmaf(yn, cy2, xn * cx2);   // ref contracted dot
            float d = (sqn + cs2) - (tt + tt);
            bool pass = act && (d < R2F);
            unsigned long long mask = __ballot(pass);
            if (pass) {
              int slot = cnt + __popcll(mask & below);
              if (slot < PCAP)
                plist[lq * PCAP + slot] =
                    ((unsigned int)csrIdx[ee] << 12) | (unsigned int)ee;
            }
            cnt += __popcll(mask);
          }
        }
      if (p == 0) pcnt[lq] = cnt;
    }
  }
  __syncthreads();

  // ---- sort: t<64 sorts packed passers ascending (== by index),
  //      first-16, self-pad with own CSR pos ----
  if (t < 64) {
    int c = min(pcnt[t], PCAP);
    unsigned int* cand = &plist[t * PCAP];
    for (int i = 1; i < c; ++i) {             // insertion sort (c ~ 1-3)
      unsigned int key = cand[i];
      int j = i - 1;
      while (j >= 0 && cand[j] > key) { cand[j + 1] = cand[j]; --j; }
      cand[j + 1] = key;
    }
    unsigned short selfPos = 0;
    if (c < KNN) {                            // self always passes -> found
      unsigned int selfIdx = (unsigned int)(lqbase + t);
      for (int i = 0; i < c; ++i)
        if ((cand[i] >> 12) == selfIdx) { selfPos = cand[i] & 4095u; break; }
    }
    if (c > KNN) c = KNN;
    for (int k = 0; k < KNN; ++k)
      idxposT[k][t] =
          (k < c) ? (unsigned short)(cand[k] & 4095u) : selfPos;
  }
  __syncthreads();

  // ---- ph3: emb from LDS CSR (wave q = slot q of every query) ----
  {
    float4 Pq = xytp4[pbase + p];             // query p's raw coords
    int m = idxposT[q][p];                    // CSR pos, q uniform
    embT[2 * q][p] = Pq.y - csrX[m];          // exact fp32 sub, same bits
    embT[2 * q + 1][p] = Pq.z - csrY[m];      // bank p%32: conflict-free
  }
  __syncthreads();                            // csrX/csrY dead after here

  // ---- ph4: wave q -> hidden units 8q..+8; k-ascending, j inner ----
  {
    const int u0 = __builtin_amdgcn_readfirstlane(q) * 8;
    float h[8];
#pragma unroll
    for (int j = 0; j < 8; ++j) h[j] = b1[u0 + j];
#pragma unroll
    for (int k = 0; k < 32; ++k) {            // ascending k, as ref
      float ek = embT[k][p];                  // conflict-free b32
      const float* __restrict__ w0 = W1 + k * 128 + u0;  // uniform
#pragma unroll
      for (int j = 0; j < 8; ++j) h[j] = fmaf(ek, w0[j], h[j]);
    }
#pragma unroll
    for (int j = 0; j < 8; ++j)
      hsT[u0 + j][p] = fmaxf(h[j], 0.f);      // overlays dead CSR region
  }
  __syncthreads();

  // ---- ph5: wave q -> outputs 4q..+4; u-ascending from b2 seed ----
  {
    const int o0 = __builtin_amdgcn_readfirstlane(q) * 4;
    float acc[4];
#pragma unroll
    for (int j = 0; j < 4; ++j) acc[j] = b2[o0 + j];
#pragma unroll 8
    for (int g = 0; g < 64; ++g) {            // u = 2g, 2g+1, ascending
      float h0 = hsT[2 * g][p];               // ds_read2-able pair
      float h1 = hsT[2 * g + 1][p];
      const float* __restrict__ w0 = W2 + (2 * g) * 64 + o0;   // uniform
#pragma unroll
      for (int j = 0; j < 4; ++j) acc[j] = fmaf(h0, w0[j], acc[j]);
#pragma unroll
      for (int j = 0; j < 4; ++j) acc[j] = fmaf(h1, w0[64 + j], acc[j]);
    }
    *(float4*)(out + (size_t)(pbase + p) * 64 + o0) =
        make_float4(acc[0], acc[1], acc[2], acc[3]);
  }
}

extern "C" void kernel_launch(void* const* d_in, const int* in_sizes, int n_in,
                              void* d_out, int out_size, void* d_ws, size_t ws_size,
                              hipStream_t stream) {
  const float4* xytp4 = (const float4*)d_in[0];  // [8,4096] (x=ch1, y=ch2)
  const float* W1 = (const float*)d_in[1];
  const float* b1 = (const float*)d_in[2];
  const float* W2 = (const float*)d_in[3];
  const float* b2 = (const float*)d_in[4];
  float* out = (float*)d_out;
  (void)d_ws; (void)ws_size;                  // workspace unused

  // MEASUREMENT: enqueue the identical, idempotent kernel twice.
  // P(k_all) = dur(this round) - dur(R12: 86.65us).
  hipLaunchKernelGGL(k_all, dim3(512), dim3(1024), 0, stream, xytp4, W1, b1,
                     W2, b2, out);
  hipLaunchKernelGGL(k_all, dim3(512), dim3(1024), 0, stream, xytp4, W1, b1,
                     W2, b2, out);
}

// Round 14
// 89.452 us; speedup vs baseline: 1.2375x; 1.2375x over previous
//
#include <hip/hip_runtime.h>

// Problem constants (fixed by the reference)
#define NB    8
#define NPTS  4096
#define KNN   16
#define CG    16          // coarse cells per axis; cell = 0.0625
#define NCC   (CG * CG)   // 256 cells per batch
#define PCAP  24          // passer cap per query (avg ~1.4; never hit)

// r^2 exactly as the reference: RADIUS = 5.0/480 in f64, squared in f64,
// rounded to f32 by weak promotion in `d2 < radius*radius`.
#define R2F ((float)((5.0 / 480.0) * (5.0 / 480.0)))
// Window half-width for cell pruning: max true pass distance
// sqrt(R2F + 5e-7) ~= 0.010441; 0.011 leaves ample margin. 2*WIN < cell.
#define WIN 0.011f

// ---- workspace layout (all written before read, every iteration) ----
// [0x00000] int    offs_g[8][NCC+1]            (8.2 KB)
// [0x10000] float4 csr_g[8][4096]              (512 KB): x, y, idx_bits, 0
#define WS_CSR 0x10000

// ---------------------------------------------------------------------------
// R13 measurement: payload = 24.0us (dur 110.70 - 86.65), and an extra
// dispatch is FREE (dur rose by exactly P -> no inter-dispatch gap in the
// graph). ~19us of payload is non-MLP: the per-block CSR build (8192
// contended LDS atomics, 1-of-16-waves prefix, scatter, 3 barriers), 64x
// redundant per batch, on every block's critical path. Fix: build ONCE per
// batch in k_build (free dispatch), k_main replaces the build with a flat
// coalesced global->LDS copy. scan/sort/ph3/ph4/ph5 are byte-identical to
// R12 (verified absmax 0.0): same LDS arrays, same stored bits, cs2
// recomputed with the same contract(off) chain.
// ---------------------------------------------------------------------------
__global__ __launch_bounds__(1024) void k_build(
    const float4* __restrict__ xytp4, int* __restrict__ offs_g,
    float4* __restrict__ csr_g) {
#pragma clang fp contract(off)
  __shared__ int offs[NCC + 1];
  __shared__ int cellcnt[NCC];

  const int t = threadIdx.x;
  const int p = t & 63;
  const int q = t >> 6;
  const int b = blockIdx.x;                   // one block per batch
  const int bb = b << 12;

  // load 4 points/thread; count cells (verified R9/R12 build logic)
  float4 Preg[4];
  int cellreg[4];
#pragma unroll
  for (int r = 0; r < 4; ++r) Preg[r] = xytp4[bb + t + 1024 * r];
  if (t < NCC) cellcnt[t] = 0;
  __syncthreads();
#pragma unroll
  for (int r = 0; r < 4; ++r) {
    int cx = min(CG - 1, max(0, (int)(Preg[r].y * (float)CG)));
    int cy = min(CG - 1, max(0, (int)(Preg[r].z * (float)CG)));
    cellreg[r] = cy * CG + cx;
    atomicAdd(&cellcnt[cellreg[r]], 1);
  }
  __syncthreads();

  // wave 0: exclusive scan of 256 counts (4 cells/lane)
  if (q == 0) {
    int b4 = p * 4;
    int s0 = cellcnt[b4], s1 = cellcnt[b4 + 1], s2 = cellcnt[b4 + 2],
        s3 = cellcnt[b4 + 3];
    int tot = s0 + s1 + s2 + s3;
    int inc = tot;
#pragma unroll
    for (int d = 1; d < 64; d <<= 1) {
      int up = __shfl_up(inc, d);
      if (p >= d) inc += up;
    }
    int ex = inc - tot;
    offs[b4] = ex; offs[b4 + 1] = ex + s0;
    offs[b4 + 2] = ex + s0 + s1; offs[b4 + 3] = ex + s0 + s1 + s2;
    if (p == 63) offs[NCC] = inc;
    cellcnt[b4] = ex; cellcnt[b4 + 1] = ex + s0;        // -> cursors
    cellcnt[b4 + 2] = ex + s0 + s1; cellcnt[b4 + 3] = ex + s0 + s1 + s2;
  }
  __syncthreads();

  // scatter straight to global CSR (order scrambled; sorted downstream)
#pragma unroll
  for (int r = 0; r < 4; ++r) {
    int pos = atomicAdd(&cellcnt[cellreg[r]], 1);
    csr_g[(b << 12) + pos] =
        make_float4(Preg[r].y, Preg[r].z,
                    __uint_as_float((unsigned)(t + 1024 * r)), 0.f);
  }
  // dump offs
  if (t < NCC + 1) offs_g[b * (NCC + 1) + t] = offs[t];
}

__global__ __launch_bounds__(1024, 8) void k_main(
    const float4* __restrict__ xytp4, const int* __restrict__ offs_g,
    const float4* __restrict__ csr_g, const float* __restrict__ W1,
    const float* __restrict__ b1, const float* __restrict__ W2,
    const float* __restrict__ b2, float* __restrict__ out) {
#pragma clang fp contract(off)
  // Region A (32KB): csrX[4096] + csrY[4096]  ->  hsT[128][64] after ph3.
  __shared__ __align__(16) char smemA[32768];
  __shared__ unsigned short csrIdx[4096];     // point index per CSR slot
  __shared__ int offs[NCC + 1];               // CSR starts
  __shared__ unsigned int plist[64 * PCAP];   // packed (idx<<12)|pos
  __shared__ int pcnt[64];
  __shared__ unsigned short idxposT[KNN][64]; // [slot][query] -> CSR pos
  __shared__ float embT[32][64];              // [k][query]

  float* csrX = (float*)smemA;                      // [4096]
  float* csrY = (float*)(smemA + 16384);            // [4096]
  float(*hsT)[64] = (float(*)[64])smemA;            // 128 x 64 (after ph3)

  const int t = threadIdx.x;
  const int p = t & 63;                       // lane
  const int q = t >> 6;                       // wave id 0..15, uniform
  const int pbase = blockIdx.x * 64;          // global query base
  const int b = pbase >> 12;                  // batch
  const int lqbase = pbase & 4095;            // batch-local query base

  // ---- stage: flat coalesced copy of the prebuilt CSR (no atomics,
  //      no prefix, no scatter -- replaces build1/2/3 + 2 barriers) ----
#pragma unroll
  for (int r = 0; r < 4; ++r) {
    int i = t + 1024 * r;
    float4 c = csr_g[(b << 12) + i];
    csrX[i] = c.x; csrY[i] = c.y;
    csrIdx[i] = (unsigned short)__float_as_uint(c.z);
  }
  if (t < NCC + 1) offs[t] = offs_g[b * (NCC + 1) + t];
  __syncthreads();

  // ---- scan: wave q, queries 4q..4q+3; <=2x2 cell window each ----
  {
    const int q0 = q * 4;
    const unsigned long long below = (1ull << p) - 1;
#pragma unroll
    for (int g = 0; g < 4; ++g) {
      int lq = q0 + g;
      float4 P = xytp4[pbase + lq];           // uniform addr -> broadcast
      float xn = P.y, yn = P.z;
      float sqn = xn * xn + yn * yn;          // ref sq chain
      int cxlo = max(0, (int)((xn - WIN) * (float)CG));
      int cxhi = min(CG - 1, (int)((xn + WIN) * (float)CG));
      int cylo = max(0, (int)((yn - WIN) * (float)CG));
      int cyhi = min(CG - 1, (int)((yn + WIN) * (float)CG));
      int cnt = 0;
      for (int cy_ = cylo; cy_ <= cyhi; ++cy_)
        for (int cx_ = cxlo; cx_ <= cxhi; ++cx_) {
          int cell = cy_ * CG + cx_;
          int st = offs[cell], en = offs[cell + 1];
          for (int base = st; base < en; base += 64) {
            int e = base + p;
            bool act = e < en;
            int ee = act ? e : st;            // clamp to a valid address
            float cx2 = csrX[ee], cy2 = csrY[ee];
            float cs2 = cx2 * cx2 + cy2 * cy2;    // == ref sq bits
            float tt = fmaf(yn, cy2, xn * cx2);   // ref contracted dot
            float d = (sqn + cs2) - (tt + tt);
            bool pass = act && (d < R2F);
            unsigned long long mask = __ballot(pass);
            if (pass) {
              int slot = cnt + __popcll(mask & below);
              if (slot < PCAP)
                plist[lq * PCAP + slot] =
                    ((unsigned int)csrIdx[ee] << 12) | (unsigned int)ee;
            }
            cnt += __popcll(mask);
          }
        }
      if (p == 0) pcnt[lq] = cnt;
    }
  }
  __syncthreads();

  // ---- sort: t<64 sorts packed passers ascending (== by index),
  //      first-16, self-pad with own CSR pos ----
  if (t < 64) {
    int c = min(pcnt[t], PCAP);
    unsigned int* cand = &plist[t * PCAP];
    for (int i = 1; i < c; ++i) {             // insertion sort (c ~ 1-3)
      unsigned int key = cand[i];
      int j = i - 1;
      while (j >= 0 && cand[j] > key) { cand[j + 1] = cand[j]; --j; }
      cand[j + 1] = key;
    }
    unsigned short selfPos = 0;
    if (c < KNN) {                            // self always passes -> found
      unsigned int selfIdx = (unsigned int)(lqbase + t);
      for (int i = 0; i < c; ++i)
        if ((cand[i] >> 12) == selfIdx) { selfPos = cand[i] & 4095u; break; }
    }
    if (c > KNN) c = KNN;
    for (int k = 0; k < KNN; ++k)
      idxposT[k][t] =
          (k < c) ? (unsigned short)(cand[k] & 4095u) : selfPos;
  }
  __syncthreads();

  // ---- ph3: emb from LDS CSR (wave q = slot q of every query) ----
  {
    float4 Pq = xytp4[pbase + p];             // query p's raw coords
    int m = idxposT[q][p];                    // CSR pos, q uniform
    embT[2 * q][p] = Pq.y - csrX[m];          // exact fp32 sub, same bits
    embT[2 * q + 1][p] = Pq.z - csrY[m];      // bank p%32: conflict-free
  }
  __syncthreads();                            // csrX/csrY dead after here

  // ---- ph4: wave q -> hidden units 8q..+8; k-ascending, j inner ----
  {
    const int u0 = __builtin_amdgcn_readfirstlane(q) * 8;
    float h[8];
#pragma unroll
    for (int j = 0; j < 8; ++j) h[j] = b1[u0 + j];
#pragma unroll
    for (int k = 0; k < 32; ++k) {            // ascending k, as ref
      float ek = embT[k][p];                  // conflict-free b32
      const float* __restrict__ w0 = W1 + k * 128 + u0;  // uniform
#pragma unroll
      for (int j = 0; j < 8; ++j) h[j] = fmaf(ek, w0[j], h[j]);
    }
#pragma unroll
    for (int j = 0; j < 8; ++j)
      hsT[u0 + j][p] = fmaxf(h[j], 0.f);      // overlays dead CSR region
  }
  __syncthreads();

  // ---- ph5: wave q -> outputs 4q..+4; u-ascending from b2 seed ----
  {
    const int o0 = __builtin_amdgcn_readfirstlane(q) * 4;
    float acc[4];
#pragma unroll
    for (int j = 0; j < 4; ++j) acc[j] = b2[o0 + j];
#pragma unroll 8
    for (int g = 0; g < 64; ++g) {            // u = 2g, 2g+1, ascending
      float h0 = hsT[2 * g][p];               // ds_read2-able pair
      float h1 = hsT[2 * g + 1][p];
      const float* __restrict__ w0 = W2 + (2 * g) * 64 + o0;   // uniform
#pragma unroll
      for (int j = 0; j < 4; ++j) acc[j] = fmaf(h0, w0[j], acc[j]);
#pragma unroll
      for (int j = 0; j < 4; ++j) acc[j] = fmaf(h1, w0[64 + j], acc[j]);
    }
    *(float4*)(out + (size_t)(pbase + p) * 64 + o0) =
        make_float4(acc[0], acc[1], acc[2], acc[3]);
  }
}

extern "C" void kernel_launch(void* const* d_in, const int* in_sizes, int n_in,
                              void* d_out, int out_size, void* d_ws, size_t ws_size,
                              hipStream_t stream) {
  const float4* xytp4 = (const float4*)d_in[0];  // [8,4096] (x=ch1, y=ch2)
  const float* W1 = (const float*)d_in[1];
  const float* b1 = (const float*)d_in[2];
  const float* W2 = (const float*)d_in[3];
  const float* b2 = (const float*)d_in[4];
  float* out = (float*)d_out;

  char* ws = (char*)d_ws;
  int* offs_g = (int*)ws;                      // [8][257]
  float4* csr_g = (float4*)(ws + WS_CSR);      // [8][4096]

  hipLaunchKernelGGL(k_build, dim3(8), dim3(1024), 0, stream, xytp4, offs_g,
                     csr_g);
  hipLaunchKernelGGL(k_main, dim3(512), dim3(1024), 0, stream, xytp4, offs_g,
                     csr_g, W1, b1, W2, b2, out);
}